// Round 12
// baseline (60.999 us; speedup 1.0000x reference)
//
#include <hip/hip_runtime.h>

// Dynamic lightweight convolution. B=8, S=2048, D=1024, K=7, H=16, L=2042.
// R12: R11 + conv LDS-issue cut:
//   - x window hoisted: 14 uint2 bf16 regs per thread (rows via LDS b64 or
//     global f32->pack for the 6-row halo), compile-time indexed.
//   - P stored bf16 [row][hq][k][4] (b64 conv reads, mostly broadcast);
//     softmax: read Lg f32 -> bar -> write P2 bf16 overlay.
// LDS 40192 B -> 4 blocks/CU; launch_bounds(512,8).

#define KK 7
#define HH 16
#define DD 1024
#define SS 2048
#define LL 2042
#define NO 112
#define TL 16
#define WTF_BYTES (7 * 32 * 64 * 8 * 2)      // 229376
#define P2OFF 32768                           // P2 bf16 [16][4][7][4] = 3584 B (overlays Lg)

typedef __attribute__((ext_vector_type(8))) short bf16x8;
typedef __attribute__((ext_vector_type(4))) float f32x4;

__device__ __forceinline__ unsigned short f2bf(float f) {
    unsigned u = __builtin_bit_cast(unsigned, f);
    u += 0x7fffu + ((u >> 16) & 1u);         // RNE
    return (unsigned short)(u >> 16);
}
__device__ __forceinline__ unsigned bfpack(float lo, float hi) {
    return (unsigned)f2bf(lo) | ((unsigned)f2bf(hi) << 16);
}
__device__ __forceinline__ float bflo(unsigned u) {
    return __builtin_bit_cast(float, u << 16);
}
__device__ __forceinline__ float bfhi(unsigned u) {
    return __builtin_bit_cast(float, u & 0xffff0000u);
}

__global__ void wprep(const float* __restrict__ W, unsigned short* __restrict__ wtf) {
    const int bx = blockIdx.x;               // 0..223 = i*32 + ks
    const int lane = threadIdx.x;
    const int i = bx >> 5, ks = bx & 31;
    const int frow = lane & 15, fq = lane >> 4;
    const int col = i * 16 + frow;
    const int k0 = ks * 32 + fq * 8;
    unsigned p[4];
#pragma unroll
    for (int j = 0; j < 4; ++j) {
        float a = W[(size_t)(k0 + 2 * j) * NO + col];
        float b = W[(size_t)(k0 + 2 * j + 1) * NO + col];
        p[j] = bfpack(a, b);
    }
    *(uint4*)(wtf + (size_t)(bx * 64 + lane) * 8) = make_uint4(p[0], p[1], p[2], p[3]);
}

// LDS (40192 B):
//   A  bf16 [16][1024] XOR-swizzled (x rows l0+6..l0+21) @ 0 .. 32768
//   Lg f32 [16][116] @ 32768 .. 40192
//   P2 bf16 [16][4][7][4] @ 32768 .. 36352 (overlay, after read-barrier)
template <bool WSOK>
__global__ __launch_bounds__(512, 8)
void dlconv(const float* __restrict__ x, const float* __restrict__ W,
            const float* __restrict__ bias, const unsigned short* __restrict__ wtf,
            float* __restrict__ out)
{
    __shared__ __align__(16) unsigned char smem[40192];
    float* Lg = (float*)(smem + 32768);      // [16][116]
    const int t  = threadIdx.x;
    const int lb = blockIdx.x, b = blockIdx.y;
    const int l0 = lb * TL;
    const float* xb = x + (size_t)b * SS * DD;

    // ---- stage x rows l0+6..l0+21 -> LDS rows 0..15 (bf16, XOR-swizzled) ----
#pragma unroll
    for (int s = 0; s < 8; ++s) {
        int idx = t + 512 * s;               // 0..4095 = 16 rows x 256 float4
        int row = idx >> 8, c4 = idx & 255;
        int gr = l0 + 6 + row; gr = gr < SS ? gr : SS - 1;
        float4 v = *(const float4*)(xb + (size_t)gr * DD + c4 * 4);
        int addr = row * 2048 + ((c4 * 8) ^ ((row & 7) << 4));
        *(uint2*)(smem + addr) = make_uint2(bfpack(v.x, v.y), bfpack(v.z, v.w));
    }
    __syncthreads();                          // B1

    // ---- GEMM: wave i (i<7) computes n-tile i (softmax index k=i) ----
    const int lane = t & 63, wid = t >> 6;
    const int frow = lane & 15, fq = lane >> 4;
    if (wid < 7) {
        const int abase = frow * 2048;
        const int aswz = (frow & 7) << 4;
        f32x4 acc = (f32x4)0.f;
#pragma unroll 8
        for (int ks = 0; ks < 32; ++ks) {
            bf16x8 af = *(const bf16x8*)(smem + abase + ((ks * 64 + fq * 16) ^ aswz));
            bf16x8 bf;
            if constexpr (WSOK) {
                bf = *(const bf16x8*)(wtf + (size_t)((wid * 32 + ks) * 64 + lane) * 8);
            } else {
                const float* wp = W + (size_t)(ks * 32 + fq * 8) * NO + wid * 16 + frow;
                short e0 = (short)f2bf(wp[0 * NO]), e1 = (short)f2bf(wp[1 * NO]);
                short e2 = (short)f2bf(wp[2 * NO]), e3 = (short)f2bf(wp[3 * NO]);
                short e4 = (short)f2bf(wp[4 * NO]), e5 = (short)f2bf(wp[5 * NO]);
                short e6 = (short)f2bf(wp[6 * NO]), e7 = (short)f2bf(wp[7 * NO]);
                bf = bf16x8{e0, e1, e2, e3, e4, e5, e6, e7};
            }
            acc = __builtin_amdgcn_mfma_f32_16x16x32_bf16(af, bf, acc, 0, 0, 0);
        }
        float bi = bias[wid * 16 + frow];
#pragma unroll
        for (int reg = 0; reg < 4; ++reg)
            Lg[(fq * 4 + reg) * 116 + wid * 16 + frow] = acc[reg] + bi;
    }
    __syncthreads();                          // B2

    // ---- softmax over k: read Lg -> regs ; bar ; write P2 bf16 overlay ----
    float v[KK];
    const int sr = t >> 4, sh = t & 15;
    if (t < 256) {
        float m = -1e30f;
#pragma unroll
        for (int i = 0; i < KK; ++i) {
            v[i] = Lg[sr * 116 + i * 16 + sh];
            m = fmaxf(m, v[i]);
        }
        float ssum = 0.f;
#pragma unroll
        for (int i = 0; i < KK; ++i) { v[i] = __expf(v[i] - m); ssum += v[i]; }
        float inv = 1.f / (7.f * ssum);       // fold mean's 1/7
#pragma unroll
        for (int i = 0; i < KK; ++i) v[i] *= inv;
    }
    __syncthreads();                          // B3: all Lg reads done
    if (t < 256) {
        const int pbase = P2OFF + sr * 224 + (sh >> 2) * 56 + (sh & 3) * 2;
#pragma unroll
        for (int i = 0; i < KK; ++i)
            *(unsigned short*)(smem + pbase + i * 8) = f2bf(v[i]);
    }
    __syncthreads();                          // B4

    // ---- conv: hoisted x window (14 uint2 bf16 regs) + P2 b64 reads ----
    const int rg = t >> 8;                   // wave-uniform: 0 -> rows 0..7, 1 -> 8..15
    const int cc = t & 255;
    const int coff = cc * 8;                 // byte offset in an LDS A row
    const int p2b = P2OFF + (cc & 3) * 56;
    float* orow0 = out + ((size_t)b * LL + l0) * DD + cc * 4;

    uint2 xw[14];
    if (rg == 0) {
        // window = x rows l0..l0+13: rows 0..5 from global f32 (L2/L3-hot), 6..13 LDS
#pragma unroll
        for (int j = 0; j < 6; ++j) {
            f32x4 g = *(const f32x4*)(xb + (size_t)(l0 + j) * DD + cc * 4);
            xw[j] = make_uint2(bfpack(g.x, g.y), bfpack(g.z, g.w));
        }
#pragma unroll
        for (int j = 6; j < 14; ++j) {
            int rr = j - 6;
            xw[j] = *(const uint2*)(smem + rr * 2048 + (coff ^ ((rr & 7) << 4)));
        }
    } else {
        // window = x rows l0+8..l0+21 = LDS rows 2..15
#pragma unroll
        for (int j = 0; j < 14; ++j) {
            int rr = j + 2;
            xw[j] = *(const uint2*)(smem + rr * 2048 + (coff ^ ((rr & 7) << 4)));
        }
    }
#pragma unroll
    for (int q = 0; q < 8; ++q) {
        int row = rg * 8 + q;
        if (l0 + row < LL) {
            f32x4 o = (f32x4)0.f;
#pragma unroll
            for (int k = 0; k < KK; ++k) {
                uint2 pp = *(const uint2*)(smem + p2b + row * 224 + k * 8);
                uint2 u = xw[q + k];          // compile-time index
                o.x += bflo(pp.x) * bflo(u.x);
                o.y += bfhi(pp.x) * bfhi(u.x);
                o.z += bflo(pp.y) * bflo(u.y);
                o.w += bfhi(pp.y) * bfhi(u.y);
            }
            *(f32x4*)(orow0 + (size_t)row * DD) = o;
        }
    }
}

extern "C" void kernel_launch(void* const* d_in, const int* in_sizes, int n_in,
                              void* d_out, int out_size, void* d_ws, size_t ws_size,
                              hipStream_t stream) {
    const float* x    = (const float*)d_in[0];
    const float* W    = (const float*)d_in[1];
    const float* bias = (const float*)d_in[2];
    float* out        = (float*)d_out;
    dim3 grid((LL + TL - 1) / TL, 8);        // 128 x 8 = 1024 blocks = 4/CU
    const bool wsok = (ws_size >= (size_t)WTF_BYTES) && d_ws != nullptr;
    if (wsok) {
        unsigned short* wtf = (unsigned short*)d_ws;
        wprep<<<224, 64, 0, stream>>>(W, wtf);
        dlconv<true><<<grid, 512, 0, stream>>>(x, W, bias, wtf, out);
    } else {
        dlconv<false><<<grid, 512, 0, stream>>>(x, W, bias, nullptr, out);
    }
}

// Round 13
// 48.452 us; speedup vs baseline: 1.2590x; 1.2590x over previous
//
#include <hip/hip_runtime.h>

// Dynamic lightweight convolution. B=8, S=2048, D=1024, K=7, H=16, L=2042.
// R13 = R12 with scratch-proof conv: conv body is template<int RG> (wave-uniform
// branch hoisted), so the 14-entry x-window array has single-path init and
// static indices -> stays in VGPRs.
//   stage x rows l0+6..l0+21 (bf16, XOR-swz, 32KB) -> waves 0..6 MFMA one
//   n-tile -> Lg f32 -> softmax (regs) -> P2 bf16 overlay -> conv:
//   x window in regs (global halo / LDS), P2 b64 broadcast reads, store out.

#define KK 7
#define HH 16
#define DD 1024
#define SS 2048
#define LL 2042
#define NO 112
#define TL 16
#define WTF_BYTES (7 * 32 * 64 * 8 * 2)      // 229376
#define P2OFF 32768                           // P2 bf16 [16][4][7][4] = 3584 B

typedef __attribute__((ext_vector_type(8))) short bf16x8;
typedef __attribute__((ext_vector_type(4))) float f32x4;

__device__ __forceinline__ unsigned short f2bf(float f) {
    unsigned u = __builtin_bit_cast(unsigned, f);
    u += 0x7fffu + ((u >> 16) & 1u);         // RNE
    return (unsigned short)(u >> 16);
}
__device__ __forceinline__ unsigned bfpack(float lo, float hi) {
    return (unsigned)f2bf(lo) | ((unsigned)f2bf(hi) << 16);
}
__device__ __forceinline__ float bflo(unsigned u) {
    return __builtin_bit_cast(float, u << 16);
}
__device__ __forceinline__ float bfhi(unsigned u) {
    return __builtin_bit_cast(float, u & 0xffff0000u);
}

__global__ void wprep(const float* __restrict__ W, unsigned short* __restrict__ wtf) {
    const int bx = blockIdx.x;               // 0..223 = i*32 + ks
    const int lane = threadIdx.x;
    const int i = bx >> 5, ks = bx & 31;
    const int frow = lane & 15, fq = lane >> 4;
    const int col = i * 16 + frow;
    const int k0 = ks * 32 + fq * 8;
    unsigned p[4];
#pragma unroll
    for (int j = 0; j < 4; ++j) {
        float a = W[(size_t)(k0 + 2 * j) * NO + col];
        float b = W[(size_t)(k0 + 2 * j + 1) * NO + col];
        p[j] = bfpack(a, b);
    }
    *(uint4*)(wtf + (size_t)(bx * 64 + lane) * 8) = make_uint4(p[0], p[1], p[2], p[3]);
}

// Conv body: RG compile-time -> single-path init, static indexing throughout.
template <int RG>
__device__ __forceinline__ void conv_body(const unsigned char* smem, const float* xb,
                                          float* out, int l0, int b, int cc)
{
    const int coff = cc * 8;                 // byte offset in an LDS A row
    const int p2b = P2OFF + (cc & 3) * 56;
    float* orow0 = out + ((size_t)b * LL + l0) * DD + cc * 4;

    uint2 xw[14];
    if constexpr (RG == 0) {
        // window rows l0..l0+13: first 6 from global f32 (L2/L3-hot), rest LDS
#pragma unroll
        for (int j = 0; j < 6; ++j) {
            f32x4 g = *(const f32x4*)(xb + (size_t)(l0 + j) * DD + cc * 4);
            xw[j] = make_uint2(bfpack(g.x, g.y), bfpack(g.z, g.w));
        }
#pragma unroll
        for (int j = 6; j < 14; ++j) {
            int rr = j - 6;
            xw[j] = *(const uint2*)(smem + rr * 2048 + (coff ^ ((rr & 7) << 4)));
        }
    } else {
        // window rows l0+8..l0+21 = LDS rows 2..15
#pragma unroll
        for (int j = 0; j < 14; ++j) {
            int rr = j + 2;
            xw[j] = *(const uint2*)(smem + rr * 2048 + (coff ^ ((rr & 7) << 4)));
        }
    }
#pragma unroll
    for (int q = 0; q < 8; ++q) {
        const int row = RG * 8 + q;
        bool ok = (RG == 0) ? true : (l0 + row < LL);
        if (ok) {
            f32x4 o = (f32x4)0.f;
#pragma unroll
            for (int k = 0; k < KK; ++k) {
                uint2 pp = *(const uint2*)(smem + p2b + row * 224 + k * 8);
                uint2 u = xw[q + k];          // compile-time index
                o.x += bflo(pp.x) * bflo(u.x);
                o.y += bfhi(pp.x) * bfhi(u.x);
                o.z += bflo(pp.y) * bflo(u.y);
                o.w += bfhi(pp.y) * bfhi(u.y);
            }
            *(f32x4*)(orow0 + (size_t)row * DD) = o;
        }
    }
}

// LDS (40192 B):
//   A  bf16 [16][1024] XOR-swizzled (x rows l0+6..l0+21) @ 0 .. 32768
//   Lg f32 [16][116] @ 32768 .. 40192
//   P2 bf16 [16][4][7][4] @ 32768 .. 36352 (overlay, after read-barrier)
template <bool WSOK>
__global__ __launch_bounds__(512, 8)
void dlconv(const float* __restrict__ x, const float* __restrict__ W,
            const float* __restrict__ bias, const unsigned short* __restrict__ wtf,
            float* __restrict__ out)
{
    __shared__ __align__(16) unsigned char smem[40192];
    float* Lg = (float*)(smem + 32768);      // [16][116]
    const int t  = threadIdx.x;
    const int lb = blockIdx.x, b = blockIdx.y;
    const int l0 = lb * TL;
    const float* xb = x + (size_t)b * SS * DD;

    // ---- stage x rows l0+6..l0+21 -> LDS rows 0..15 (bf16, XOR-swizzled) ----
#pragma unroll
    for (int s = 0; s < 8; ++s) {
        int idx = t + 512 * s;               // 0..4095 = 16 rows x 256 float4
        int row = idx >> 8, c4 = idx & 255;
        int gr = l0 + 6 + row; gr = gr < SS ? gr : SS - 1;
        float4 v = *(const float4*)(xb + (size_t)gr * DD + c4 * 4);
        int addr = row * 2048 + ((c4 * 8) ^ ((row & 7) << 4));
        *(uint2*)(smem + addr) = make_uint2(bfpack(v.x, v.y), bfpack(v.z, v.w));
    }
    __syncthreads();                          // B1

    // ---- GEMM: wave i (i<7) computes n-tile i (softmax index k=i) ----
    const int lane = t & 63, wid = t >> 6;
    const int frow = lane & 15, fq = lane >> 4;
    if (wid < 7) {
        const int abase = frow * 2048;
        const int aswz = (frow & 7) << 4;
        f32x4 acc = (f32x4)0.f;
#pragma unroll 8
        for (int ks = 0; ks < 32; ++ks) {
            bf16x8 af = *(const bf16x8*)(smem + abase + ((ks * 64 + fq * 16) ^ aswz));
            bf16x8 bf;
            if constexpr (WSOK) {
                bf = *(const bf16x8*)(wtf + (size_t)((wid * 32 + ks) * 64 + lane) * 8);
            } else {
                const float* wp = W + (size_t)(ks * 32 + fq * 8) * NO + wid * 16 + frow;
                short e0 = (short)f2bf(wp[0 * NO]), e1 = (short)f2bf(wp[1 * NO]);
                short e2 = (short)f2bf(wp[2 * NO]), e3 = (short)f2bf(wp[3 * NO]);
                short e4 = (short)f2bf(wp[4 * NO]), e5 = (short)f2bf(wp[5 * NO]);
                short e6 = (short)f2bf(wp[6 * NO]), e7 = (short)f2bf(wp[7 * NO]);
                bf = bf16x8{e0, e1, e2, e3, e4, e5, e6, e7};
            }
            acc = __builtin_amdgcn_mfma_f32_16x16x32_bf16(af, bf, acc, 0, 0, 0);
        }
        float bi = bias[wid * 16 + frow];
#pragma unroll
        for (int reg = 0; reg < 4; ++reg)
            Lg[(fq * 4 + reg) * 116 + wid * 16 + frow] = acc[reg] + bi;
    }
    __syncthreads();                          // B2

    // ---- softmax over k: read Lg -> regs ; bar ; write P2 bf16 overlay ----
    float v[KK];
    const int sr = t >> 4, sh = t & 15;
    if (t < 256) {
        float m = -1e30f;
#pragma unroll
        for (int i = 0; i < KK; ++i) {
            v[i] = Lg[sr * 116 + i * 16 + sh];
            m = fmaxf(m, v[i]);
        }
        float ssum = 0.f;
#pragma unroll
        for (int i = 0; i < KK; ++i) { v[i] = __expf(v[i] - m); ssum += v[i]; }
        float inv = 1.f / (7.f * ssum);       // fold mean's 1/7
#pragma unroll
        for (int i = 0; i < KK; ++i) v[i] *= inv;
    }
    __syncthreads();                          // B3: all Lg reads done
    if (t < 256) {
        const int pbase = P2OFF + sr * 224 + (sh >> 2) * 56 + (sh & 3) * 2;
#pragma unroll
        for (int i = 0; i < KK; ++i)
            *(unsigned short*)(smem + pbase + i * 8) = f2bf(v[i]);
    }
    __syncthreads();                          // B4

    // ---- conv, wave-uniform split; template kills the merged-array phi ----
    const int cc = t & 255;
    if ((t >> 8) == 0) conv_body<0>(smem, xb, out, l0, b, cc);
    else               conv_body<1>(smem, xb, out, l0, b, cc);
}

extern "C" void kernel_launch(void* const* d_in, const int* in_sizes, int n_in,
                              void* d_out, int out_size, void* d_ws, size_t ws_size,
                              hipStream_t stream) {
    const float* x    = (const float*)d_in[0];
    const float* W    = (const float*)d_in[1];
    const float* bias = (const float*)d_in[2];
    float* out        = (float*)d_out;
    dim3 grid((LL + TL - 1) / TL, 8);        // 128 x 8 = 1024 blocks = 4/CU
    const bool wsok = (ws_size >= (size_t)WTF_BYTES) && d_ws != nullptr;
    if (wsok) {
        unsigned short* wtf = (unsigned short*)d_ws;
        wprep<<<224, 64, 0, stream>>>(W, wtf);
        dlconv<true><<<grid, 512, 0, stream>>>(x, W, bias, wtf, out);
    } else {
        dlconv<false><<<grid, 512, 0, stream>>>(x, W, bias, nullptr, out);
    }
}

// Round 14
// 44.066 us; speedup vs baseline: 1.3843x; 1.0995x over previous
//
#include <hip/hip_runtime.h>

// Dynamic lightweight convolution. B=8, S=2048, D=1024, K=7, H=16, L=2042.
// R14: conv re-mapped to 4 rows x 8 channels per thread, all-b128 LDS, no
// register arrays (spill-proof):
//   stage x rows l0+6..l0+21 (bf16, XOR-swz, 32KB) -> waves 0..6 MFMA one
//   n-tile -> Lg f32 -> softmax (regs) -> P2 bf16 [16][2][7][8] overlay ->
//   conv: per (row,k) one b128 P + one b128 x (LDS) or 2 f32x4 global (halo).

#define KK 7
#define HH 16
#define DD 1024
#define SS 2048
#define LL 2042
#define NO 112
#define TL 16
#define WTF_BYTES (7 * 32 * 64 * 8 * 2)      // 229376
#define P2OFF 32768                           // P2 bf16 [16][2][7][8] = 3584 B

typedef __attribute__((ext_vector_type(8))) short bf16x8;
typedef __attribute__((ext_vector_type(4))) float f32x4;

__device__ __forceinline__ unsigned short f2bf(float f) {
    unsigned u = __builtin_bit_cast(unsigned, f);
    u += 0x7fffu + ((u >> 16) & 1u);         // RNE
    return (unsigned short)(u >> 16);
}
__device__ __forceinline__ unsigned bfpack(float lo, float hi) {
    return (unsigned)f2bf(lo) | ((unsigned)f2bf(hi) << 16);
}
__device__ __forceinline__ float bflo(unsigned u) {
    return __builtin_bit_cast(float, u << 16);
}
__device__ __forceinline__ float bfhi(unsigned u) {
    return __builtin_bit_cast(float, u & 0xffff0000u);
}

__global__ void wprep(const float* __restrict__ W, unsigned short* __restrict__ wtf) {
    const int bx = blockIdx.x;               // 0..223 = i*32 + ks
    const int lane = threadIdx.x;
    const int i = bx >> 5, ks = bx & 31;
    const int frow = lane & 15, fq = lane >> 4;
    const int col = i * 16 + frow;
    const int k0 = ks * 32 + fq * 8;
    unsigned p[4];
#pragma unroll
    for (int j = 0; j < 4; ++j) {
        float a = W[(size_t)(k0 + 2 * j) * NO + col];
        float b = W[(size_t)(k0 + 2 * j + 1) * NO + col];
        p[j] = bfpack(a, b);
    }
    *(uint4*)(wtf + (size_t)(bx * 64 + lane) * 8) = make_uint4(p[0], p[1], p[2], p[3]);
}

// Conv body: RG = row-group (rows RG*4..RG*4+3). All indices compile-time
// after unroll; no register arrays.
template <int RG>
__device__ __forceinline__ void conv_body(const unsigned char* smem, const float* xb,
                                          float* out, int l0, int b, int co)
{
    const int hh = co & 1;                   // h-half: channels d0=co*8 -> h = hh*8..+7
    const int coff = co * 16;                // byte offset of this oct in an LDS row
    float* obase = out + ((size_t)b * LL + l0) * DD + co * 8;
#pragma unroll
    for (int r = 0; r < 4; ++r) {
        const int row = RG * 4 + r;
        if (l0 + row < LL) {
            f32x4 o0 = (f32x4)0.f, o1 = (f32x4)0.f;
#pragma unroll
            for (int k = 0; k < KK; ++k) {
                const uint4 pv = *(const uint4*)(smem + P2OFF + row * 224 + hh * 112 + k * 16);
                const int rx = row + k;      // x row in window space 0..21
                if (rx < 6) {
                    // halo: f32 direct from global (L2-hot; l0+rx <= 2037 < SS)
                    const float* gp = xb + (size_t)(l0 + rx) * DD + co * 8;
                    f32x4 g0 = *(const f32x4*)gp;
                    f32x4 g1 = *(const f32x4*)(gp + 4);
                    o0.x += bflo(pv.x) * g0.x; o0.y += bfhi(pv.x) * g0.y;
                    o0.z += bflo(pv.y) * g0.z; o0.w += bfhi(pv.y) * g0.w;
                    o1.x += bflo(pv.z) * g1.x; o1.y += bfhi(pv.z) * g1.y;
                    o1.z += bflo(pv.w) * g1.z; o1.w += bfhi(pv.w) * g1.w;
                } else {
                    const int rr = rx - 6;   // LDS row 0..15
                    const uint4 u = *(const uint4*)(smem + rr * 2048 + (coff ^ ((rr & 7) << 4)));
                    o0.x += bflo(pv.x) * bflo(u.x); o0.y += bfhi(pv.x) * bfhi(u.x);
                    o0.z += bflo(pv.y) * bflo(u.y); o0.w += bfhi(pv.y) * bfhi(u.y);
                    o1.x += bflo(pv.z) * bflo(u.z); o1.y += bfhi(pv.z) * bfhi(u.z);
                    o1.z += bflo(pv.w) * bflo(u.w); o1.w += bfhi(pv.w) * bfhi(u.w);
                }
            }
            *(f32x4*)(obase + (size_t)row * DD) = o0;
            *(f32x4*)(obase + (size_t)row * DD + 4) = o1;
        }
    }
}

// LDS (40192 B):
//   A  bf16 [16][1024] XOR-swizzled (x rows l0+6..l0+21) @ 0 .. 32768
//   Lg f32 [16][116] @ 32768 .. 40192
//   P2 bf16 [16][2][7][8] @ 32768 .. 36352 (overlay, after B3 read-barrier)
template <bool WSOK>
__global__ __launch_bounds__(512, 4)
void dlconv(const float* __restrict__ x, const float* __restrict__ W,
            const float* __restrict__ bias, const unsigned short* __restrict__ wtf,
            float* __restrict__ out)
{
    __shared__ __align__(16) unsigned char smem[40192];
    float* Lg = (float*)(smem + 32768);      // [16][116]
    const int t  = threadIdx.x;
    const int lb = blockIdx.x, b = blockIdx.y;
    const int l0 = lb * TL;
    const float* xb = x + (size_t)b * SS * DD;

    // ---- stage x rows l0+6..l0+21 -> LDS rows 0..15 (bf16, XOR-swizzled) ----
#pragma unroll
    for (int s = 0; s < 8; ++s) {
        int idx = t + 512 * s;               // 0..4095 = 16 rows x 256 float4
        int row = idx >> 8, c4 = idx & 255;
        int gr = l0 + 6 + row; gr = gr < SS ? gr : SS - 1;
        float4 v = *(const float4*)(xb + (size_t)gr * DD + c4 * 4);
        int addr = row * 2048 + ((c4 * 8) ^ ((row & 7) << 4));
        *(uint2*)(smem + addr) = make_uint2(bfpack(v.x, v.y), bfpack(v.z, v.w));
    }
    __syncthreads();                          // B1

    // ---- GEMM: wave i (i<7) computes n-tile i (softmax index k=i) ----
    const int lane = t & 63, wid = t >> 6;
    const int frow = lane & 15, fq = lane >> 4;
    if (wid < 7) {
        const int abase = frow * 2048;
        const int aswz = (frow & 7) << 4;
        f32x4 acc = (f32x4)0.f;
#pragma unroll 8
        for (int ks = 0; ks < 32; ++ks) {
            bf16x8 af = *(const bf16x8*)(smem + abase + ((ks * 64 + fq * 16) ^ aswz));
            bf16x8 bf;
            if constexpr (WSOK) {
                bf = *(const bf16x8*)(wtf + (size_t)((wid * 32 + ks) * 64 + lane) * 8);
            } else {
                const float* wp = W + (size_t)(ks * 32 + fq * 8) * NO + wid * 16 + frow;
                short e0 = (short)f2bf(wp[0 * NO]), e1 = (short)f2bf(wp[1 * NO]);
                short e2 = (short)f2bf(wp[2 * NO]), e3 = (short)f2bf(wp[3 * NO]);
                short e4 = (short)f2bf(wp[4 * NO]), e5 = (short)f2bf(wp[5 * NO]);
                short e6 = (short)f2bf(wp[6 * NO]), e7 = (short)f2bf(wp[7 * NO]);
                bf = bf16x8{e0, e1, e2, e3, e4, e5, e6, e7};
            }
            acc = __builtin_amdgcn_mfma_f32_16x16x32_bf16(af, bf, acc, 0, 0, 0);
        }
        float bi = bias[wid * 16 + frow];
#pragma unroll
        for (int reg = 0; reg < 4; ++reg)
            Lg[(fq * 4 + reg) * 116 + wid * 16 + frow] = acc[reg] + bi;
    }
    __syncthreads();                          // B2

    // ---- softmax over k: read Lg -> regs ; bar ; write P2 bf16 overlay ----
    float v[KK];
    const int sr = t >> 4, sh = t & 15;
    if (t < 256) {
        float m = -1e30f;
#pragma unroll
        for (int i = 0; i < KK; ++i) {
            v[i] = Lg[sr * 116 + i * 16 + sh];
            m = fmaxf(m, v[i]);
        }
        float ssum = 0.f;
#pragma unroll
        for (int i = 0; i < KK; ++i) { v[i] = __expf(v[i] - m); ssum += v[i]; }
        float inv = 1.f / (7.f * ssum);       // fold mean's 1/7
#pragma unroll
        for (int i = 0; i < KK; ++i) v[i] *= inv;
    }
    __syncthreads();                          // B3: all Lg reads done
    if (t < 256) {
        // P2[sr][sh>>3][i][sh&7] bf16: row stride 224 B, half 112 B, k 16 B
        const int pbase = P2OFF + sr * 224 + (sh >> 3) * 112 + (sh & 7) * 2;
#pragma unroll
        for (int i = 0; i < KK; ++i)
            *(unsigned short*)(smem + pbase + i * 16) = f2bf(v[i]);
    }
    __syncthreads();                          // B4

    // ---- conv: rgrp = t>>7 (wave-uniform), col-oct co = t&127 ----
    const int co = t & 127;
    const int rgrp = t >> 7;
    if (rgrp == 0)      conv_body<0>(smem, xb, out, l0, b, co);
    else if (rgrp == 1) conv_body<1>(smem, xb, out, l0, b, co);
    else if (rgrp == 2) conv_body<2>(smem, xb, out, l0, b, co);
    else                conv_body<3>(smem, xb, out, l0, b, co);
}

extern "C" void kernel_launch(void* const* d_in, const int* in_sizes, int n_in,
                              void* d_out, int out_size, void* d_ws, size_t ws_size,
                              hipStream_t stream) {
    const float* x    = (const float*)d_in[0];
    const float* W    = (const float*)d_in[1];
    const float* bias = (const float*)d_in[2];
    float* out        = (float*)d_out;
    dim3 grid((LL + TL - 1) / TL, 8);        // 128 x 8 = 1024 blocks = 4/CU
    const bool wsok = (ws_size >= (size_t)WTF_BYTES) && d_ws != nullptr;
    if (wsok) {
        unsigned short* wtf = (unsigned short*)d_ws;
        wprep<<<224, 64, 0, stream>>>(W, wtf);
        dlconv<true><<<grid, 512, 0, stream>>>(x, W, bias, wtf, out);
    } else {
        dlconv<false><<<grid, 512, 0, stream>>>(x, W, bias, nullptr, out);
    }
}